// Round 1
// baseline (883.523 us; speedup 1.0000x reference)
//
#include <hip/hip_runtime.h>
#include <math.h>

#define BATCH 2048
#define SEQ   22
#define INSZ  1000
#define HID   128
#define G3    384          // 3*HID
#define MTOT  (BATCH*SEQ)  // 45056

// ---------------------------------------------------------------------------
// Kernel A: x_gates[m, n] = sum_k inputs[m, k] * W_ih[n, k] + b_ih[n]
// M=45056, N=384, K=1000.  128x128 tile, BK=16, 256 threads, 8x8 per thread.
// ---------------------------------------------------------------------------
__global__ __launch_bounds__(256)
void xgates_gemm(const float* __restrict__ A,     // [MTOT][INSZ]
                 const float* __restrict__ W,     // [G3][INSZ]
                 const float* __restrict__ bias,  // [G3]
                 float* __restrict__ C)           // [MTOT][G3]
{
    __shared__ float As[16][132];   // [k][m] transposed, padded (2-way max)
    __shared__ float Bs[16][132];   // [k][n]

    const int tid = threadIdx.x;
    const int m0  = blockIdx.x * 128;
    const int n0  = blockIdx.y * 128;
    const int row = tid >> 2;   // 0..63
    const int fq  = tid & 3;    // 0..3 (which float4 of the 16-wide k-slab)
    const int tx  = tid & 15;
    const int ty  = tid >> 4;

    float acc[8][8];
#pragma unroll
    for (int i = 0; i < 8; ++i)
#pragma unroll
        for (int j = 0; j < 8; ++j) acc[i][j] = 0.f;

    for (int kt = 0; kt < 63; ++kt) {          // 62*16 + 8 = 1000 (zero-padded)
        const int kk = kt * 16 + fq * 4;
        const bool v = (kk < INSZ);            // INSZ%4==0 -> float4-exact guard
        float4 a0 = make_float4(0.f, 0.f, 0.f, 0.f), a1 = a0, w0 = a0, w1 = a0;
        if (v) {
            a0 = *(const float4*)&A[(size_t)(m0 + row) * INSZ + kk];
            a1 = *(const float4*)&A[(size_t)(m0 + row + 64) * INSZ + kk];
            w0 = *(const float4*)&W[(size_t)(n0 + row) * INSZ + kk];
            w1 = *(const float4*)&W[(size_t)(n0 + row + 64) * INSZ + kk];
        }
        __syncthreads();   // previous iteration's LDS reads complete
        As[fq*4+0][row]    = a0.x; As[fq*4+1][row]    = a0.y;
        As[fq*4+2][row]    = a0.z; As[fq*4+3][row]    = a0.w;
        As[fq*4+0][row+64] = a1.x; As[fq*4+1][row+64] = a1.y;
        As[fq*4+2][row+64] = a1.z; As[fq*4+3][row+64] = a1.w;
        Bs[fq*4+0][row]    = w0.x; Bs[fq*4+1][row]    = w0.y;
        Bs[fq*4+2][row]    = w0.z; Bs[fq*4+3][row]    = w0.w;
        Bs[fq*4+0][row+64] = w1.x; Bs[fq*4+1][row+64] = w1.y;
        Bs[fq*4+2][row+64] = w1.z; Bs[fq*4+3][row+64] = w1.w;
        __syncthreads();

#pragma unroll
        for (int k = 0; k < 16; ++k) {
            const float4 a0v = *(const float4*)&As[k][ty * 4];
            const float4 a1v = *(const float4*)&As[k][ty * 4 + 64];
            const float4 b0v = *(const float4*)&Bs[k][tx * 4];
            const float4 b1v = *(const float4*)&Bs[k][tx * 4 + 64];
            const float aR[8] = {a0v.x, a0v.y, a0v.z, a0v.w,
                                 a1v.x, a1v.y, a1v.z, a1v.w};
            const float bR[8] = {b0v.x, b0v.y, b0v.z, b0v.w,
                                 b1v.x, b1v.y, b1v.z, b1v.w};
#pragma unroll
            for (int i = 0; i < 8; ++i)
#pragma unroll
                for (int j = 0; j < 8; ++j)
                    acc[i][j] = fmaf(aR[i], bR[j], acc[i][j]);
        }
    }

    const float4 bv0 = *(const float4*)&bias[n0 + tx * 4];
    const float4 bv1 = *(const float4*)&bias[n0 + 64 + tx * 4];
#pragma unroll
    for (int i = 0; i < 8; ++i) {
        const int m = m0 + (i >> 2) * 64 + ty * 4 + (i & 3);
        float4 r0v, r1v;
        r0v.x = acc[i][0] + bv0.x; r0v.y = acc[i][1] + bv0.y;
        r0v.z = acc[i][2] + bv0.z; r0v.w = acc[i][3] + bv0.w;
        r1v.x = acc[i][4] + bv1.x; r1v.y = acc[i][5] + bv1.y;
        r1v.z = acc[i][6] + bv1.z; r1v.w = acc[i][7] + bv1.w;
        *(float4*)&C[(size_t)m * G3 + n0 + tx * 4]      = r0v;
        *(float4*)&C[(size_t)m * G3 + n0 + 64 + tx * 4] = r1v;
    }
}

// ---------------------------------------------------------------------------
// One-time transpose of W_hh for coalesced access in the scan:
// Wt4[js*384 + g] = float4(W_hh[g][4*js .. 4*js+3]),  js in [0,32), g in [0,384)
// ---------------------------------------------------------------------------
__global__ __launch_bounds__(256)
void transpose_whh(const float4* __restrict__ Whh4, float4* __restrict__ Wt4)
{
    const int idx = blockIdx.x * 256 + threadIdx.x;  // < 12288
    const int js = idx / G3;
    const int g  = idx - js * G3;
    Wt4[idx] = Whh4[g * 32 + js];
}

// ---------------------------------------------------------------------------
// Kernel B: full GRU scan. One workgroup owns 8 batch rows for all 22 steps.
// 256 threads: thread = (rb in {0,1}) x (gb in [0,128)) -> 4 rows x 3 gates.
// h lives in LDS; hg staged in LDS for the elementwise phase.
// ---------------------------------------------------------------------------
__global__ __launch_bounds__(256)
void gru_scan(const float* __restrict__ xg,     // [MTOT][G3], row m=b*SEQ+t
              const float* __restrict__ h0,     // [BATCH][HID]
              const float4* __restrict__ Wt,    // [32][G3] as float4
              const float* __restrict__ b_hh,   // [G3]
              float* __restrict__ outs)         // [BATCH][SEQ*HID]
{
    __shared__ float hs[8][132];    // padded: bank = (4r+j)%32
    __shared__ float hgs[8][388];

    const int tid = threadIdx.x;
    const int b0  = blockIdx.x << 3;       // 8 rows per block
    const int gb  = tid & 127;
    const int rb  = tid >> 7;
    const int g0  = gb * 3;
    const int r0  = rb * 4;

#pragma unroll
    for (int k2 = 0; k2 < 4; ++k2) {
        const int idx = (k2 << 8) + tid;
        const int r = idx >> 7, j = idx & 127;
        hs[r][j] = h0[((size_t)(b0 + r) << 7) + j];
    }
    const float bb0 = b_hh[g0], bb1 = b_hh[g0 + 1], bb2 = b_hh[g0 + 2];
    __syncthreads();

    for (int t = 0; t < SEQ; ++t) {
        float acc[4][3];
#pragma unroll
        for (int ri = 0; ri < 4; ++ri) {
            acc[ri][0] = 0.f; acc[ri][1] = 0.f; acc[ri][2] = 0.f;
        }
#pragma unroll 4
        for (int js = 0; js < 32; ++js) {
            const float4 w0 = Wt[js * G3 + g0];
            const float4 w1 = Wt[js * G3 + g0 + 1];
            const float4 w2 = Wt[js * G3 + g0 + 2];
#pragma unroll
            for (int ri = 0; ri < 4; ++ri) {
                const float4 h4 = *(const float4*)&hs[r0 + ri][js << 2];
                acc[ri][0] = fmaf(h4.x, w0.x, fmaf(h4.y, w0.y,
                             fmaf(h4.z, w0.z, fmaf(h4.w, w0.w, acc[ri][0]))));
                acc[ri][1] = fmaf(h4.x, w1.x, fmaf(h4.y, w1.y,
                             fmaf(h4.z, w1.z, fmaf(h4.w, w1.w, acc[ri][1]))));
                acc[ri][2] = fmaf(h4.x, w2.x, fmaf(h4.y, w2.y,
                             fmaf(h4.z, w2.z, fmaf(h4.w, w2.w, acc[ri][2]))));
            }
        }
#pragma unroll
        for (int ri = 0; ri < 4; ++ri) {
            hgs[r0 + ri][g0]     = acc[ri][0] + bb0;
            hgs[r0 + ri][g0 + 1] = acc[ri][1] + bb1;
            hgs[r0 + ri][g0 + 2] = acc[ri][2] + bb2;
        }
        __syncthreads();

        // elementwise gate update: 8 rows x 128 = 1024 cells, 4 per thread
#pragma unroll
        for (int k2 = 0; k2 < 4; ++k2) {
            const int idx = (k2 << 8) + tid;
            const int r = idx >> 7, j = idx & 127;
            const size_t base = ((size_t)(b0 + r) * SEQ + t) * G3;
            const float xr = xg[base + j];
            const float xz = xg[base + 128 + j];
            const float xn = xg[base + 256 + j];
            const float hr = hgs[r][j];
            const float hz = hgs[r][128 + j];
            const float hn = hgs[r][256 + j];
            const float rr = 1.f / (1.f + __expf(-(xr + hr)));
            const float zz = 1.f / (1.f + __expf(-(xz + hz)));
            float vv = xn + rr * hn;
            vv = fminf(fmaxf(vv, -20.f), 20.f);       // tanh saturates; avoid inf/inf
            const float e2 = __expf(2.f * vv);
            const float nn = (e2 - 1.f) / (e2 + 1.f); // tanh(vv)
            const float hp = hs[r][j];
            const float hnew = fmaf(zz, hp - nn, nn); // (1-z)*n + z*h
            hs[r][j] = hnew;
            outs[(size_t)(b0 + r) * (SEQ * HID) + (t << 7) + j] = hnew;
        }
        __syncthreads();
    }
}

// ---------------------------------------------------------------------------
// Kernel C: out[b][c] = outs[b][:] . W_dec[c][:] + b_dec[c]
// One wave per batch row; 4 waves per block.
// ---------------------------------------------------------------------------
__global__ __launch_bounds__(256)
void decoder(const float* __restrict__ outs,   // [BATCH][2816]
             const float* __restrict__ Wd,     // [4][2816]
             const float* __restrict__ bd,     // [4]
             float* __restrict__ out)          // [BATCH][4]
{
    const int tid  = threadIdx.x;
    const int wave = tid >> 6;
    const int lane = tid & 63;
    const int b    = blockIdx.x * 4 + wave;

    const float4* row4 = (const float4*)&outs[(size_t)b * (SEQ * HID)];
    const float4* Wd4  = (const float4*)Wd;   // [4][704]

    float acc[4] = {0.f, 0.f, 0.f, 0.f};
    for (int it = 0; it < 11; ++it) {          // 704 float4 / 64 lanes
        const int o4 = it * 64 + lane;
        const float4 x = row4[o4];
#pragma unroll
        for (int c = 0; c < 4; ++c) {
            const float4 w = Wd4[c * 704 + o4];
            acc[c] += x.x * w.x + x.y * w.y + x.z * w.z + x.w * w.w;
        }
    }
#pragma unroll
    for (int c = 0; c < 4; ++c) {
        float v = acc[c];
        for (int off = 32; off > 0; off >>= 1) v += __shfl_down(v, off, 64);
        if (lane == 0) out[b * 4 + c] = v + bd[c];
    }
}

// ---------------------------------------------------------------------------
extern "C" void kernel_launch(void* const* d_in, const int* in_sizes, int n_in,
                              void* d_out, int out_size, void* d_ws, size_t ws_size,
                              hipStream_t stream)
{
    const float* inputs = (const float*)d_in[0];   // [2048][22][1000]
    const float* h0     = (const float*)d_in[1];   // [1][2048][128]
    const float* W_ih   = (const float*)d_in[2];   // [384][1000]
    const float* W_hh   = (const float*)d_in[3];   // [384][128]
    const float* b_ih   = (const float*)d_in[4];   // [384]
    const float* b_hh   = (const float*)d_in[5];   // [384]
    const float* W_dec  = (const float*)d_in[6];   // [4][2816]
    const float* b_dec  = (const float*)d_in[7];   // [4]
    float* out = (float*)d_out;                    // [2048][4]

    char* ws = (char*)d_ws;
    float*  xg   = (float*)ws;                                   // 45056*384 f32 (69.2 MB)
    float*  outs = (float*)(ws + (size_t)MTOT * G3 * 4);         // 2048*2816 f32 (23.1 MB)
    float4* Wt   = (float4*)(ws + (size_t)MTOT * G3 * 4
                                + (size_t)BATCH * SEQ * HID * 4); // 12288 float4 (0.2 MB)

    hipLaunchKernelGGL(transpose_whh, dim3(48), dim3(256), 0, stream,
                       (const float4*)W_hh, Wt);
    hipLaunchKernelGGL(xgates_gemm, dim3(MTOT / 128, G3 / 128), dim3(256), 0, stream,
                       inputs, W_ih, b_ih, xg);
    hipLaunchKernelGGL(gru_scan, dim3(BATCH / 8), dim3(256), 0, stream,
                       xg, h0, (const float4*)Wt, b_hh, outs);
    hipLaunchKernelGGL(decoder, dim3(BATCH / 4), dim3(256), 0, stream,
                       outs, W_dec, b_dec, out);
}

// Round 2
// 617.671 us; speedup vs baseline: 1.4304x; 1.4304x over previous
//
#include <hip/hip_runtime.h>
#include <math.h>

#define BATCH 2048
#define SEQ   22
#define INSZ  1000
#define HID   128
#define G3    384            // 3*HID
#define MTOT  (BATCH*SEQ)    // 45056
#define KPAD  1024           // K padded for MFMA

typedef __attribute__((ext_vector_type(8))) short bf16x8_t;   // 8 bf16 (4 VGPRs)
typedef __attribute__((ext_vector_type(4))) float f32x4_t;    // 4 fp32 acc

typedef __attribute__((address_space(3))) ushort lds_us_t;
typedef __attribute__((address_space(1))) const ushort gbl_us_t;

__device__ inline void gload16(const ushort* g, ushort* l) {
    __builtin_amdgcn_global_load_lds((gbl_us_t*)g, (lds_us_t*)l, 16, 0, 0);
}

__device__ inline ushort bf16_rn(float x) {
    uint u = __float_as_uint(x);
    uint r = u + 0x7FFFu + ((u >> 16) & 1u);
    return (ushort)(r >> 16);
}
__device__ inline void split1(float a, ushort& h, ushort& l) {
    h = bf16_rn(a);
    const float fh = __uint_as_float(((uint)h) << 16);
    l = bf16_rn(a - fh);
}

// ---------------------------------------------------------------------------
// Split fp32 rows [nrows][INSZ] -> bf16 hi/lo [nrows][KPAD] (zero-padded K).
// ---------------------------------------------------------------------------
__global__ __launch_bounds__(256)
void split_rows(const float* __restrict__ A, ushort* __restrict__ Hi,
                ushort* __restrict__ Lo, int nrows)
{
    const int nG = nrows * (KPAD / 4);
    for (int g = blockIdx.x * 256 + threadIdx.x; g < nG; g += gridDim.x * 256) {
        const int m = g >> 8;
        const int k = (g & 255) * 4;
        float4 v = make_float4(0.f, 0.f, 0.f, 0.f);
        if (k < INSZ) v = *(const float4*)&A[(size_t)m * INSZ + k];  // INSZ%4==0
        ushort4 h, l;
        split1(v.x, h.x, l.x); split1(v.y, h.y, l.y);
        split1(v.z, h.z, l.z); split1(v.w, h.w, l.w);
        *(ushort4*)&Hi[(size_t)m * KPAD + k] = h;
        *(ushort4*)&Lo[(size_t)m * KPAD + k] = l;
    }
}

// ---------------------------------------------------------------------------
// MFMA GEMM: C[m][n] = sum_k A[m][k]*W[n][k] + bias[n], fp32 via bf16 3-term
// split. M=45056, N=384, K=1024. 128x128 tile, BK=32, 4 waves, 64x64/wave.
// LDS: Ah/Al/Bh/Bl each [128 rows][32 k] bf16 = 8KB -> 32KB total.
// Chunk swizzle (both-sides): 16B-chunk c' = c ^ ((row>>1)&3)  -> 2-way free.
// ---------------------------------------------------------------------------
__global__ __launch_bounds__(256)
void mfma_gemm(const ushort* __restrict__ Ah, const ushort* __restrict__ Al,
               const ushort* __restrict__ Bh, const ushort* __restrict__ Bl,
               const float* __restrict__ bias, float* __restrict__ C)
{
    __shared__ ushort lds[4 * 128 * 32];  // [Ah|Al|Bh|Bl], 4096 ushorts each

    const int tid  = threadIdx.x;
    const int lane = tid & 63;
    const int wid  = tid >> 6;

    // XCD-bijective mapping: all 3 n-tiles of one m-panel on one XCD.
    // 1056 blocks = 8 XCD * 44 m * 3 n
    const int d = blockIdx.x;
    const int xcd = d & 7, s = d >> 3;          // s in [0,132)
    const int m0 = (xcd * 44 + s / 3) * 128;
    const int n0 = (s % 3) * 128;

    const int wm = (wid >> 1) * 64;             // wave tile origin in M
    const int wn = (wid & 1) * 64;              // ... in N

    // staging geometry: per array, wave handles segments {2*wid, 2*wid+1};
    // slot s_=seg*64+lane -> row=s_>>2, chunk-slot p=s_&3, source chunk p^f(row)
    const int seg0 = wid * 2;
    int rowS[2], chS[2];
#pragma unroll
    for (int i = 0; i < 2; ++i) {
        const int s_ = (seg0 + i) * 64 + lane;
        rowS[i] = s_ >> 2;
        chS[i]  = (s_ & 3) ^ ((rowS[i] >> 1) & 3);
    }

    f32x4_t acc[4][4];
#pragma unroll
    for (int i = 0; i < 4; ++i)
#pragma unroll
        for (int j = 0; j < 4; ++j) acc[i][j] = {0.f, 0.f, 0.f, 0.f};

    for (int kt = 0; kt < KPAD / 32; ++kt) {
        __syncthreads();   // previous iteration's LDS reads complete
        const int kOff = kt * 32;
#pragma unroll
        for (int i = 0; i < 2; ++i) {
            const size_t goA = (size_t)(m0 + rowS[i]) * KPAD + kOff + chS[i] * 8;
            const size_t goB = (size_t)(n0 + rowS[i]) * KPAD + kOff + chS[i] * 8;
            const int lb = (seg0 + i) * 512;   // wave-uniform elem offset
            gload16(Ah + goA, &lds[lb]);
            gload16(Al + goA, &lds[4096 + lb]);
            gload16(Bh + goB, &lds[8192 + lb]);
            gload16(Bl + goB, &lds[12288 + lb]);
        }
        __syncthreads();   // drains vmcnt -> staged data visible

        bf16x8_t ah[4], al[4], bh[4], bl[4];
#pragma unroll
        for (int f = 0; f < 4; ++f) {
            {
                const int row = wm + f * 16 + (lane & 15);
                const int c   = (lane >> 4) ^ ((row >> 1) & 3);
                const int eo  = row * 32 + c * 8;
                ah[f] = *(const bf16x8_t*)&lds[eo];
                al[f] = *(const bf16x8_t*)&lds[4096 + eo];
            }
            {
                const int row = wn + f * 16 + (lane & 15);
                const int c   = (lane >> 4) ^ ((row >> 1) & 3);
                const int eo  = row * 32 + c * 8;
                bh[f] = *(const bf16x8_t*)&lds[8192 + eo];
                bl[f] = *(const bf16x8_t*)&lds[12288 + eo];
            }
        }
#pragma unroll
        for (int mf = 0; mf < 4; ++mf)
#pragma unroll
            for (int nf = 0; nf < 4; ++nf) {
                acc[mf][nf] = __builtin_amdgcn_mfma_f32_16x16x32_bf16(
                    ah[mf], bh[nf], acc[mf][nf], 0, 0, 0);
                acc[mf][nf] = __builtin_amdgcn_mfma_f32_16x16x32_bf16(
                    ah[mf], bl[nf], acc[mf][nf], 0, 0, 0);
                acc[mf][nf] = __builtin_amdgcn_mfma_f32_16x16x32_bf16(
                    al[mf], bh[nf], acc[mf][nf], 0, 0, 0);
            }
    }

    // epilogue: C/D layout col=lane&15, row=(lane>>4)*4+q  [m89-verified]
#pragma unroll
    for (int nf = 0; nf < 4; ++nf) {
        const int gn = n0 + wn + nf * 16 + (lane & 15);
        const float bv = bias[gn];
#pragma unroll
        for (int mf = 0; mf < 4; ++mf) {
#pragma unroll
            for (int q = 0; q < 4; ++q) {
                const int gm = m0 + wm + mf * 16 + (lane >> 4) * 4 + q;
                C[(size_t)gm * G3 + gn] = acc[mf][nf][q] + bv;
            }
        }
    }
}

// ---------------------------------------------------------------------------
// W_hh [384][128] f32 -> Wt layout [js][q][gb] float4:
// Wt[(js*3+q)*128 + gb] = float4(W_hh[3*gb+q][4*js .. 4*js+3])
// so scan lane gb reads coalesced float4s.
// ---------------------------------------------------------------------------
__global__ __launch_bounds__(256)
void transpose_whh(const float4* __restrict__ Whh4, float4* __restrict__ Wt4)
{
    const int idx = blockIdx.x * 256 + threadIdx.x;  // < 12288
    const int js  = idx / 384;
    const int rem = idx - js * 384;
    const int q   = rem >> 7;
    const int gb  = rem & 127;
    Wt4[idx] = Whh4[(3 * gb + q) * 32 + js];
}

// ---------------------------------------------------------------------------
// GRU scan: 256 blocks x 512 threads, 8 batch rows per block, all 22 steps.
// thread = (gb in [0,128) -> 3 gates) x (rp in [0,4) -> 2 rows).
// ---------------------------------------------------------------------------
__global__ __launch_bounds__(512)
void gru_scan(const float* __restrict__ xg,     // [MTOT][G3], row m=b*SEQ+t
              const float* __restrict__ h0,     // [BATCH][HID]
              const float4* __restrict__ Wt,    // [32][3][128] float4
              const float* __restrict__ b_hh,   // [G3]
              float* __restrict__ outs)         // [BATCH][SEQ*HID]
{
    __shared__ float hs[8][132];
    __shared__ float hgs[8][388];

    const int tid = threadIdx.x;
    const int b0  = blockIdx.x << 3;
    const int gb  = tid & 127;
    const int rp  = tid >> 7;        // 0..3
    const int g0  = gb * 3;
    const int r0  = rp * 2;

#pragma unroll
    for (int k2 = 0; k2 < 2; ++k2) {
        const int idx = (k2 << 9) + tid;
        const int r = idx >> 7, j = idx & 127;
        hs[r][j] = h0[((size_t)(b0 + r) << 7) + j];
    }
    const float bb0 = b_hh[g0], bb1 = b_hh[g0 + 1], bb2 = b_hh[g0 + 2];
    __syncthreads();

    for (int t = 0; t < SEQ; ++t) {
        float a00 = 0.f, a01 = 0.f, a02 = 0.f;
        float a10 = 0.f, a11 = 0.f, a12 = 0.f;
#pragma unroll 8
        for (int js = 0; js < 32; ++js) {
            const float4 w0 = Wt[(js * 3 + 0) * 128 + gb];
            const float4 w1 = Wt[(js * 3 + 1) * 128 + gb];
            const float4 w2 = Wt[(js * 3 + 2) * 128 + gb];
            const float4 hA = *(const float4*)&hs[r0][js << 2];
            const float4 hB = *(const float4*)&hs[r0 + 1][js << 2];
            a00 = fmaf(hA.x, w0.x, fmaf(hA.y, w0.y, fmaf(hA.z, w0.z, fmaf(hA.w, w0.w, a00))));
            a01 = fmaf(hA.x, w1.x, fmaf(hA.y, w1.y, fmaf(hA.z, w1.z, fmaf(hA.w, w1.w, a01))));
            a02 = fmaf(hA.x, w2.x, fmaf(hA.y, w2.y, fmaf(hA.z, w2.z, fmaf(hA.w, w2.w, a02))));
            a10 = fmaf(hB.x, w0.x, fmaf(hB.y, w0.y, fmaf(hB.z, w0.z, fmaf(hB.w, w0.w, a10))));
            a11 = fmaf(hB.x, w1.x, fmaf(hB.y, w1.y, fmaf(hB.z, w1.z, fmaf(hB.w, w1.w, a11))));
            a12 = fmaf(hB.x, w2.x, fmaf(hB.y, w2.y, fmaf(hB.z, w2.z, fmaf(hB.w, w2.w, a12))));
        }
        hgs[r0][g0]     = a00 + bb0; hgs[r0][g0 + 1]     = a01 + bb1; hgs[r0][g0 + 2]     = a02 + bb2;
        hgs[r0 + 1][g0] = a10 + bb0; hgs[r0 + 1][g0 + 1] = a11 + bb1; hgs[r0 + 1][g0 + 2] = a12 + bb2;
        __syncthreads();

        // elementwise: 8 rows x 128 = 1024 cells, 2 per thread
#pragma unroll
        for (int k2 = 0; k2 < 2; ++k2) {
            const int idx = (k2 << 9) + tid;
            const int r = idx >> 7, j = idx & 127;
            const size_t base = ((size_t)(b0 + r) * SEQ + t) * G3;
            const float xr = xg[base + j];
            const float xz = xg[base + 128 + j];
            const float xn = xg[base + 256 + j];
            const float hr = hgs[r][j];
            const float hz = hgs[r][128 + j];
            const float hn = hgs[r][256 + j];
            const float rr = 1.f / (1.f + __expf(-(xr + hr)));
            const float zz = 1.f / (1.f + __expf(-(xz + hz)));
            float vv = xn + rr * hn;
            vv = fminf(fmaxf(vv, -20.f), 20.f);
            const float e2 = __expf(2.f * vv);
            const float nn = (e2 - 1.f) / (e2 + 1.f);   // tanh
            const float hp = hs[r][j];
            const float hnew = fmaf(zz, hp - nn, nn);   // (1-z)*n + z*h
            hs[r][j] = hnew;
            outs[(size_t)(b0 + r) * (SEQ * HID) + (t << 7) + j] = hnew;
        }
        __syncthreads();
    }
}

// ---------------------------------------------------------------------------
// Decoder: out[b][c] = outs[b][:] . W_dec[c][:] + b_dec[c]
// ---------------------------------------------------------------------------
__global__ __launch_bounds__(256)
void decoder(const float* __restrict__ outs,   // [BATCH][2816]
             const float* __restrict__ Wd,     // [4][2816]
             const float* __restrict__ bd,     // [4]
             float* __restrict__ out)          // [BATCH][4]
{
    const int tid  = threadIdx.x;
    const int wave = tid >> 6;
    const int lane = tid & 63;
    const int b    = blockIdx.x * 4 + wave;

    const float4* row4 = (const float4*)&outs[(size_t)b * (SEQ * HID)];
    const float4* Wd4  = (const float4*)Wd;   // [4][704]

    float acc[4] = {0.f, 0.f, 0.f, 0.f};
    for (int it = 0; it < 11; ++it) {
        const int o4 = it * 64 + lane;
        const float4 x = row4[o4];
#pragma unroll
        for (int c = 0; c < 4; ++c) {
            const float4 w = Wd4[c * 704 + o4];
            acc[c] += x.x * w.x + x.y * w.y + x.z * w.z + x.w * w.w;
        }
    }
#pragma unroll
    for (int c = 0; c < 4; ++c) {
        float v = acc[c];
        for (int off = 32; off > 0; off >>= 1) v += __shfl_down(v, off, 64);
        if (lane == 0) out[b * 4 + c] = v + bd[c];
    }
}

// ---------------------------------------------------------------------------
extern "C" void kernel_launch(void* const* d_in, const int* in_sizes, int n_in,
                              void* d_out, int out_size, void* d_ws, size_t ws_size,
                              hipStream_t stream)
{
    const float* inputs = (const float*)d_in[0];   // [2048][22][1000]
    const float* h0     = (const float*)d_in[1];   // [1][2048][128]
    const float* W_ih   = (const float*)d_in[2];   // [384][1000]
    const float* W_hh   = (const float*)d_in[3];   // [384][128]
    const float* b_ih   = (const float*)d_in[4];   // [384]
    const float* b_hh   = (const float*)d_in[5];   // [384]
    const float* W_dec  = (const float*)d_in[6];   // [4][2816]
    const float* b_dec  = (const float*)d_in[7];   // [4]
    float* out = (float*)d_out;                    // [2048][4]

    // workspace layout (16B-aligned offsets)
    char* ws = (char*)d_ws;
    const size_t szAh = (size_t)MTOT * KPAD * 2;       // 92,274,688
    const size_t szB  = (size_t)G3 * KPAD * 2;         // 786,432
    ushort* A_hi = (ushort*)ws;
    ushort* A_lo = (ushort*)(ws + szAh);
    ushort* B_hi = (ushort*)(ws + 2 * szAh);
    ushort* B_lo = (ushort*)(ws + 2 * szAh + szB);
    float4* Wt   = (float4*)(ws + 2 * szAh + 2 * szB);             // 196,608 B
    float*  xgm  = (float*)(ws + 2 * szAh + 2 * szB + 196608);     // 69,206,016 B
    float*  outs = (float*)A_hi;   // alias: A_hi dead once mfma_gemm finishes

    hipLaunchKernelGGL(split_rows, dim3(2048), dim3(256), 0, stream,
                       inputs, A_hi, A_lo, MTOT);
    hipLaunchKernelGGL(split_rows, dim3(384), dim3(256), 0, stream,
                       W_ih, B_hi, B_lo, G3);
    hipLaunchKernelGGL(transpose_whh, dim3(48), dim3(256), 0, stream,
                       (const float4*)W_hh, Wt);
    hipLaunchKernelGGL(mfma_gemm, dim3(1056), dim3(256), 0, stream,
                       A_hi, A_lo, B_hi, B_lo, b_ih, xgm);
    hipLaunchKernelGGL(gru_scan, dim3(BATCH / 8), dim3(512), 0, stream,
                       xgm, h0, (const float4*)Wt, b_hh, outs);
    hipLaunchKernelGGL(decoder, dim3(BATCH / 4), dim3(256), 0, stream,
                       outs, W_dec, b_dec, out);
}

// Round 3
// 546.849 us; speedup vs baseline: 1.6157x; 1.1295x over previous
//
#include <hip/hip_runtime.h>
#include <math.h>

#define BATCH 2048
#define SEQ   22
#define INSZ  1000
#define HID   128
#define G3    384            // 3*HID
#define MTOT  (BATCH*SEQ)    // 45056
#define KPAD  1024           // K padded for MFMA
#define DECW  (SEQ*HID)      // 2816

typedef __attribute__((ext_vector_type(8))) short  bf16x8_t;
typedef __attribute__((ext_vector_type(4))) float  f32x4_t;
typedef __attribute__((ext_vector_type(8))) ushort us8_t;

typedef __attribute__((address_space(3))) ushort lds_us_t;
typedef __attribute__((address_space(1))) const ushort gbl_us_t;

__device__ inline void gload16(const ushort* g, ushort* l) {
    __builtin_amdgcn_global_load_lds((gbl_us_t*)g, (lds_us_t*)l, 16, 0, 0);
}

__device__ inline ushort bf16_rn(float x) {
    uint u = __float_as_uint(x);
    uint r = u + 0x7FFFu + ((u >> 16) & 1u);
    return (ushort)(r >> 16);
}
__device__ inline void split1(float a, ushort& h, ushort& l) {
    h = bf16_rn(a);
    const float fh = __uint_as_float(((uint)h) << 16);
    l = bf16_rn(a - fh);
}

// ---------------------------------------------------------------------------
// Split fp32 rows [nrows][INSZ] -> bf16 hi/lo [nrows][KPAD], 8 elems/thread
// (16B stores).
// ---------------------------------------------------------------------------
__global__ __launch_bounds__(256)
void split_rows(const float* __restrict__ A, ushort* __restrict__ Hi,
                ushort* __restrict__ Lo, int nrows)
{
    const int nG = nrows * (KPAD / 8);
    for (int g = blockIdx.x * 256 + threadIdx.x; g < nG; g += gridDim.x * 256) {
        const int m = g >> 7;
        const int k = (g & 127) * 8;
        float4 v0 = make_float4(0.f, 0.f, 0.f, 0.f), v1 = v0;
        if (k < INSZ) {                      // INSZ%8==0 -> both quads valid
            v0 = *(const float4*)&A[(size_t)m * INSZ + k];
            v1 = *(const float4*)&A[(size_t)m * INSZ + k + 4];
        }
        us8_t h, l;
        split1(v0.x, ((ushort*)&h)[0], ((ushort*)&l)[0]);
        split1(v0.y, ((ushort*)&h)[1], ((ushort*)&l)[1]);
        split1(v0.z, ((ushort*)&h)[2], ((ushort*)&l)[2]);
        split1(v0.w, ((ushort*)&h)[3], ((ushort*)&l)[3]);
        split1(v1.x, ((ushort*)&h)[4], ((ushort*)&l)[4]);
        split1(v1.y, ((ushort*)&h)[5], ((ushort*)&l)[5]);
        split1(v1.z, ((ushort*)&h)[6], ((ushort*)&l)[6]);
        split1(v1.w, ((ushort*)&h)[7], ((ushort*)&l)[7]);
        *(us8_t*)&Hi[(size_t)m * KPAD + k] = h;
        *(us8_t*)&Lo[(size_t)m * KPAD + k] = l;
    }
}

// ---------------------------------------------------------------------------
// MFMA GEMM (unchanged from r2, passed): C = A*W^T + bias via bf16 3-term.
// ---------------------------------------------------------------------------
__global__ __launch_bounds__(256)
void mfma_gemm(const ushort* __restrict__ Ah, const ushort* __restrict__ Al,
               const ushort* __restrict__ Bh, const ushort* __restrict__ Bl,
               const float* __restrict__ bias, float* __restrict__ C)
{
    __shared__ ushort lds[4 * 128 * 32];

    const int tid  = threadIdx.x;
    const int lane = tid & 63;
    const int wid  = tid >> 6;

    const int d = blockIdx.x;
    const int xcd = d & 7, s = d >> 3;
    const int m0 = (xcd * 44 + s / 3) * 128;
    const int n0 = (s % 3) * 128;

    const int wm = (wid >> 1) * 64;
    const int wn = (wid & 1) * 64;

    const int seg0 = wid * 2;
    int rowS[2], chS[2];
#pragma unroll
    for (int i = 0; i < 2; ++i) {
        const int s_ = (seg0 + i) * 64 + lane;
        rowS[i] = s_ >> 2;
        chS[i]  = (s_ & 3) ^ ((rowS[i] >> 1) & 3);
    }

    f32x4_t acc[4][4];
#pragma unroll
    for (int i = 0; i < 4; ++i)
#pragma unroll
        for (int j = 0; j < 4; ++j) acc[i][j] = {0.f, 0.f, 0.f, 0.f};

    for (int kt = 0; kt < KPAD / 32; ++kt) {
        __syncthreads();
        const int kOff = kt * 32;
#pragma unroll
        for (int i = 0; i < 2; ++i) {
            const size_t goA = (size_t)(m0 + rowS[i]) * KPAD + kOff + chS[i] * 8;
            const size_t goB = (size_t)(n0 + rowS[i]) * KPAD + kOff + chS[i] * 8;
            const int lb = (seg0 + i) * 512;
            gload16(Ah + goA, &lds[lb]);
            gload16(Al + goA, &lds[4096 + lb]);
            gload16(Bh + goB, &lds[8192 + lb]);
            gload16(Bl + goB, &lds[12288 + lb]);
        }
        __syncthreads();

        bf16x8_t ah[4], al[4], bh[4], bl[4];
#pragma unroll
        for (int f = 0; f < 4; ++f) {
            {
                const int row = wm + f * 16 + (lane & 15);
                const int c   = (lane >> 4) ^ ((row >> 1) & 3);
                const int eo  = row * 32 + c * 8;
                ah[f] = *(const bf16x8_t*)&lds[eo];
                al[f] = *(const bf16x8_t*)&lds[4096 + eo];
            }
            {
                const int row = wn + f * 16 + (lane & 15);
                const int c   = (lane >> 4) ^ ((row >> 1) & 3);
                const int eo  = row * 32 + c * 8;
                bh[f] = *(const bf16x8_t*)&lds[8192 + eo];
                bl[f] = *(const bf16x8_t*)&lds[12288 + eo];
            }
        }
#pragma unroll
        for (int mf = 0; mf < 4; ++mf)
#pragma unroll
            for (int nf = 0; nf < 4; ++nf) {
                acc[mf][nf] = __builtin_amdgcn_mfma_f32_16x16x32_bf16(
                    ah[mf], bh[nf], acc[mf][nf], 0, 0, 0);
                acc[mf][nf] = __builtin_amdgcn_mfma_f32_16x16x32_bf16(
                    ah[mf], bl[nf], acc[mf][nf], 0, 0, 0);
                acc[mf][nf] = __builtin_amdgcn_mfma_f32_16x16x32_bf16(
                    al[mf], bh[nf], acc[mf][nf], 0, 0, 0);
            }
    }

#pragma unroll
    for (int nf = 0; nf < 4; ++nf) {
        const int gn = n0 + wn + nf * 16 + (lane & 15);
        const float bv = bias[gn];
#pragma unroll
        for (int mf = 0; mf < 4; ++mf) {
#pragma unroll
            for (int q = 0; q < 4; ++q) {
                const int gm = m0 + wm + mf * 16 + (lane >> 4) * 4 + q;
                C[(size_t)gm * G3 + gn] = acc[mf][nf][q] + bv;
            }
        }
    }
}

// ---------------------------------------------------------------------------
// W_hh [384][128] f32 -> Wt float4 layout [k4][g]:
// Wt4[k4*384 + g] = float4(W_hh[g][4*k4 .. 4*k4+3]);  scan reads lane-coalesced.
// ---------------------------------------------------------------------------
__global__ __launch_bounds__(256)
void transpose_whh(const float4* __restrict__ Whh4, float4* __restrict__ Wt4)
{
    const int idx = blockIdx.x * 256 + threadIdx.x;  // < 12288
    const int k4  = idx / G3;
    const int g   = idx - k4 * G3;
    Wt4[idx] = Whh4[g * 32 + k4];
}

// ---------------------------------------------------------------------------
// GRU scan + fused decoder. 256 blocks x 768 threads, 8 batch rows/block.
// thread = (jh = tid/384, g = tid%384): owns W_hh[g][jh*64..+64) in 16 VGPR
// float4s -> zero W memory traffic in the t-loop. Partial dots reduced via
// LDS (2 halves per gate). outs kept in LDS (90 KB); decoder runs in-block.
// ---------------------------------------------------------------------------
__global__ __launch_bounds__(768)
void gru_scan_dec(const float* __restrict__ xg,    // [MTOT][G3], m=b*SEQ+t
                  const float* __restrict__ h0,    // [BATCH][HID]
                  const float4* __restrict__ Wt,   // [32][384] float4
                  const float* __restrict__ b_hh,  // [G3]
                  const float* __restrict__ Wd,    // [4][2816]
                  const float* __restrict__ bd,    // [4]
                  float* __restrict__ out)         // [BATCH][4]
{
    __shared__ float hs[8][132];          //  4.2 KB
    __shared__ float pp[8][2][G3];        // 24.6 KB
    __shared__ float outsL[8][DECW];      // 90.1 KB   (total ~119 KB)

    const int tid = threadIdx.x;
    const int b0  = blockIdx.x << 3;
    const int jh  = tid / G3;             // 0 or 1 (wave-uniform: 384 = 6 waves)
    const int g   = tid - jh * G3;        // 0..383

    // W slice into registers: w[q] = W_hh[g][jh*64 + 4q .. +4]
    float4 w[16];
#pragma unroll
    for (int q = 0; q < 16; ++q) w[q] = Wt[(jh * 16 + q) * G3 + g];
    const float addb = jh ? b_hh[g] : 0.f;

    // init h
    for (int idx = tid; idx < 1024; idx += 768)
        hs[idx >> 7][idx & 127] = h0[((size_t)(b0 + (idx >> 7)) << 7) + (idx & 127)];
    __syncthreads();

    // elementwise-cell ownership: cell0 = tid, cell1 = tid+768 (if <1024)
    const int r_0 = tid >> 7,        j_0 = tid & 127;
    const int r_1 = (tid + 768) >> 7, j_1 = tid & 127;   // (tid+768)&127 == tid&127
    const bool has1 = (tid < 256);

    for (int t = 0; t < SEQ; ++t) {
        // prefetch this step's xg into VGPRs (hides under the matvec)
        const size_t base0 = ((size_t)(b0 + r_0) * SEQ + t) * G3;
        const float xr0 = xg[base0 + j_0];
        const float xz0 = xg[base0 + 128 + j_0];
        const float xn0 = xg[base0 + 256 + j_0];
        float xr1 = 0.f, xz1 = 0.f, xn1 = 0.f;
        if (has1) {
            const size_t base1 = ((size_t)(b0 + r_1) * SEQ + t) * G3;
            xr1 = xg[base1 + j_1];
            xz1 = xg[base1 + 128 + j_1];
            xn1 = xg[base1 + 256 + j_1];
        }

        // matvec: acc[r] = W[g][jh-half] . h[r][jh-half]
        float acc[8] = {0.f, 0.f, 0.f, 0.f, 0.f, 0.f, 0.f, 0.f};
#pragma unroll
        for (int q = 0; q < 16; ++q) {
            const float4 wq = w[q];
            const int ho = (jh * 16 + q) << 2;
#pragma unroll
            for (int r = 0; r < 8; ++r) {
                const float4 h4 = *(const float4*)&hs[r][ho];  // wave-uniform bcast
                acc[r] = fmaf(h4.x, wq.x, fmaf(h4.y, wq.y,
                         fmaf(h4.z, wq.z, fmaf(h4.w, wq.w, acc[r]))));
            }
        }
#pragma unroll
        for (int r = 0; r < 8; ++r) pp[r][jh][g] = acc[r] + addb;
        __syncthreads();

        // elementwise gate update (each cell owned by exactly one thread-slot)
        {
            const float hr = pp[r_0][0][j_0]       + pp[r_0][1][j_0];
            const float hz = pp[r_0][0][128 + j_0] + pp[r_0][1][128 + j_0];
            const float hn = pp[r_0][0][256 + j_0] + pp[r_0][1][256 + j_0];
            const float rr = 1.f / (1.f + __expf(-(xr0 + hr)));
            const float zz = 1.f / (1.f + __expf(-(xz0 + hz)));
            float vv = xn0 + rr * hn;
            vv = fminf(fmaxf(vv, -20.f), 20.f);
            const float e2 = __expf(2.f * vv);
            const float nn = (e2 - 1.f) / (e2 + 1.f);
            const float hp = hs[r_0][j_0];
            const float hnew = fmaf(zz, hp - nn, nn);
            hs[r_0][j_0] = hnew;
            outsL[r_0][(t << 7) + j_0] = hnew;
        }
        if (has1) {
            const float hr = pp[r_1][0][j_1]       + pp[r_1][1][j_1];
            const float hz = pp[r_1][0][128 + j_1] + pp[r_1][1][128 + j_1];
            const float hn = pp[r_1][0][256 + j_1] + pp[r_1][1][256 + j_1];
            const float rr = 1.f / (1.f + __expf(-(xr1 + hr)));
            const float zz = 1.f / (1.f + __expf(-(xz1 + hz)));
            float vv = xn1 + rr * hn;
            vv = fminf(fmaxf(vv, -20.f), 20.f);
            const float e2 = __expf(2.f * vv);
            const float nn = (e2 - 1.f) / (e2 + 1.f);
            const float hp = hs[r_1][j_1];
            const float hnew = fmaf(zz, hp - nn, nn);
            hs[r_1][j_1] = hnew;
            outsL[r_1][(t << 7) + j_1] = hnew;
        }
        __syncthreads();
    }

    // fused decoder: wave w<8 handles row w. 2816 = 64 lanes x 44.
    const int wv = tid >> 6, lane = tid & 63;
    if (wv < 8) {
        float da[4] = {0.f, 0.f, 0.f, 0.f};
        for (int i = 0; i < 44; ++i) {
            const float v = outsL[wv][i * 64 + lane];
#pragma unroll
            for (int c = 0; c < 4; ++c)
                da[c] = fmaf(v, Wd[(size_t)c * DECW + i * 64 + lane], da[c]);
        }
#pragma unroll
        for (int c = 0; c < 4; ++c) {
            float v = da[c];
            for (int off = 32; off > 0; off >>= 1) v += __shfl_down(v, off, 64);
            if (lane == 0) out[(b0 + wv) * 4 + c] = v + bd[c];
        }
    }
}

// ---------------------------------------------------------------------------
extern "C" void kernel_launch(void* const* d_in, const int* in_sizes, int n_in,
                              void* d_out, int out_size, void* d_ws, size_t ws_size,
                              hipStream_t stream)
{
    const float* inputs = (const float*)d_in[0];   // [2048][22][1000]
    const float* h0     = (const float*)d_in[1];   // [1][2048][128]
    const float* W_ih   = (const float*)d_in[2];   // [384][1000]
    const float* W_hh   = (const float*)d_in[3];   // [384][128]
    const float* b_ih   = (const float*)d_in[4];   // [384]
    const float* b_hh   = (const float*)d_in[5];   // [384]
    const float* W_dec  = (const float*)d_in[6];   // [4][2816]
    const float* b_dec  = (const float*)d_in[7];   // [4]
    float* out = (float*)d_out;                    // [2048][4]

    char* ws = (char*)d_ws;
    const size_t szAh = (size_t)MTOT * KPAD * 2;       // 92,274,688
    const size_t szB  = (size_t)G3 * KPAD * 2;         // 786,432
    ushort* A_hi = (ushort*)ws;
    ushort* A_lo = (ushort*)(ws + szAh);
    ushort* B_hi = (ushort*)(ws + 2 * szAh);
    ushort* B_lo = (ushort*)(ws + 2 * szAh + szB);
    float4* Wt   = (float4*)(ws + 2 * szAh + 2 * szB);             // 196,608 B
    float*  xgm  = (float*)(ws + 2 * szAh + 2 * szB + 196608);     // 69,206,016 B

    hipLaunchKernelGGL(split_rows, dim3(2048), dim3(256), 0, stream,
                       inputs, A_hi, A_lo, MTOT);
    hipLaunchKernelGGL(split_rows, dim3(192), dim3(256), 0, stream,
                       W_ih, B_hi, B_lo, G3);
    hipLaunchKernelGGL(transpose_whh, dim3(48), dim3(256), 0, stream,
                       (const float4*)W_hh, Wt);
    hipLaunchKernelGGL(mfma_gemm, dim3(1056), dim3(256), 0, stream,
                       A_hi, A_lo, B_hi, B_lo, b_ih, xgm);
    hipLaunchKernelGGL(gru_scan_dec, dim3(BATCH / 8), dim3(768), 0, stream,
                       xgm, h0, (const float4*)Wt, b_hh, W_dec, b_dec, out);
}

// Round 4
// 509.029 us; speedup vs baseline: 1.7357x; 1.0743x over previous
//
#include <hip/hip_runtime.h>
#include <hip/hip_bf16.h>
#include <math.h>

#define BATCH 2048
#define SEQ   22
#define INSZ  1000
#define HID   128
#define G3    384            // 3*HID
#define MTOT  (BATCH*SEQ)    // 45056
#define KPAD  1024           // K padded (B only)
#define DECW  (SEQ*HID)      // 2816

typedef __attribute__((ext_vector_type(8))) short  bf16x8_t;
typedef __attribute__((ext_vector_type(4))) float  f32x4_t;
typedef __attribute__((ext_vector_type(8))) ushort us8_t;

typedef __attribute__((address_space(3))) ushort lds_us_t;
typedef __attribute__((address_space(1))) const ushort gbl_us_t;

__device__ inline void gload16u(const ushort* g, ushort* l) {
    __builtin_amdgcn_global_load_lds((gbl_us_t*)g, (lds_us_t*)l, 16, 0, 0);
}
__device__ inline void gload16f(const float* g, float* l) {
    __builtin_amdgcn_global_load_lds((gbl_us_t*)g, (lds_us_t*)l, 16, 0, 0);
}

__device__ inline ushort bf16_rn(float x) {
    uint u = __float_as_uint(x);
    uint r = u + 0x7FFFu + ((u >> 16) & 1u);
    return (ushort)(r >> 16);
}
__device__ inline void split1(float a, ushort& h, ushort& l) {
    h = bf16_rn(a);
    const float fh = __uint_as_float(((uint)h) << 16);
    l = bf16_rn(a - fh);
}

// 8 f32 (two float4, k-order) -> packed bf16 hi + lo fragments
__device__ inline void cvt8(const float4 p0, const float4 p1,
                            bf16x8_t& hi, bf16x8_t& lo)
{
    const float f[8] = {p0.x, p0.y, p0.z, p0.w, p1.x, p1.y, p1.z, p1.w};
    union { uint u[4]; bf16x8_t v; } H, L;
#pragma unroll
    for (int i = 0; i < 4; ++i) {
        const float2 v = make_float2(f[2 * i], f[2 * i + 1]);
        __hip_bfloat162 h2 = __float22bfloat162_rn(v);
        const uint w = *(const uint*)&h2;
        H.u[i] = w;
        const float fx = __uint_as_float(w << 16);
        const float fy = __uint_as_float(w & 0xFFFF0000u);
        const float2 r = make_float2(f[2 * i] - fx, f[2 * i + 1] - fy);
        __hip_bfloat162 l2 = __float22bfloat162_rn(r);
        L.u[i] = *(const uint*)&l2;
    }
    hi = H.v; lo = L.v;
}

// ---------------------------------------------------------------------------
// Split fp32 rows [nrows][INSZ] -> bf16 hi/lo [nrows][KPAD] (W_ih only now).
// ---------------------------------------------------------------------------
__global__ __launch_bounds__(256)
void split_rows(const float* __restrict__ A, ushort* __restrict__ Hi,
                ushort* __restrict__ Lo, int nrows)
{
    const int nG = nrows * (KPAD / 8);
    for (int g = blockIdx.x * 256 + threadIdx.x; g < nG; g += gridDim.x * 256) {
        const int m = g >> 7;
        const int k = (g & 127) * 8;
        float4 v0 = make_float4(0.f, 0.f, 0.f, 0.f), v1 = v0;
        if (k < INSZ) {
            v0 = *(const float4*)&A[(size_t)m * INSZ + k];
            v1 = *(const float4*)&A[(size_t)m * INSZ + k + 4];
        }
        us8_t h, l;
        split1(v0.x, ((ushort*)&h)[0], ((ushort*)&l)[0]);
        split1(v0.y, ((ushort*)&h)[1], ((ushort*)&l)[1]);
        split1(v0.z, ((ushort*)&h)[2], ((ushort*)&l)[2]);
        split1(v0.w, ((ushort*)&h)[3], ((ushort*)&l)[3]);
        split1(v1.x, ((ushort*)&h)[4], ((ushort*)&l)[4]);
        split1(v1.y, ((ushort*)&h)[5], ((ushort*)&l)[5]);
        split1(v1.z, ((ushort*)&h)[6], ((ushort*)&l)[6]);
        split1(v1.w, ((ushort*)&h)[7], ((ushort*)&l)[7]);
        *(us8_t*)&Hi[(size_t)m * KPAD + k] = h;
        *(us8_t*)&Lo[(size_t)m * KPAD + k] = l;
    }
}

// ---------------------------------------------------------------------------
// MFMA GEMM, fused A-split, double-buffered (T3 2-phase):
// C[m][n] = sum_k A[m][k] W[n][k] + bias[n].  M=45056, N=384, K=1000.
// 128x128 tile, BK=32, 4 waves (64x64 each). A staged fp32, converted to
// bf16 hi/lo in-register. B pre-split bf16 (zero-padded K=1024) -> tail-k
// products vanish. LDS 64 KB (2 bufs) -> 2 blocks/CU.
// ---------------------------------------------------------------------------
__global__ __launch_bounds__(256, 2)
void mfma_gemm(const float* __restrict__ A,      // [MTOT][1000] fp32
               const ushort* __restrict__ Bh,    // [G3][KPAD] bf16 hi
               const ushort* __restrict__ Bl,    // [G3][KPAD] bf16 lo
               const float* __restrict__ bias, float* __restrict__ C)
{
    __shared__ float  ldsA[2][4096];    // [buf][row*32 + chunk4f32]  16 KB each
    __shared__ ushort ldsBh[2][4096];   // [buf][row*32 + c*8]         8 KB each
    __shared__ ushort ldsBl[2][4096];

    const int tid  = threadIdx.x;
    const int lane = tid & 63;
    const int wid  = tid >> 6;

    // XCD-bijective mapping: 1056 blocks = 8 XCD x 44 m-panels x 3 n
    const int d = blockIdx.x;
    const int xcd = d & 7, s = d >> 3;
    const int m0 = (xcd * 44 + s / 3) * 128;
    const int n0 = (s % 3) * 128;

    const int wm = (wid >> 1) * 64;
    const int wn = (wid & 1) * 64;

    // staging constants (derived: row&7 == lane>>3 for A; chB lane-only)
    const int gcA = (lane & 7) ^ (lane >> 3);            // A swizzled chunk
    const int chB = (lane & 3) ^ ((lane >> 3) & 3);      // B swizzled chunk

    f32x4_t acc[4][4];
#pragma unroll
    for (int i = 0; i < 4; ++i)
#pragma unroll
        for (int j = 0; j < 4; ++j) acc[i][j] = {0.f, 0.f, 0.f, 0.f};

#define STAGE(KT, PB)                                                          \
    {                                                                          \
        const int kt_ = (KT);                                                  \
        _Pragma("unroll")                                                      \
        for (int u = 0; u < 4; ++u) {                                          \
            const int rowA = wid * 32 + u * 8 + (lane >> 3);                   \
            int gc = gcA;                                                      \
            if (kt_ == 31 && gc >= 2) gc = 0;  /* clamp: garbage*0, no OOB */  \
            gload16f(A + (size_t)(m0 + rowA) * INSZ + kt_ * 32 + gc * 4,       \
                     &ldsA[PB][(wid * 4 + u) * 256 + lane * 4]);               \
        }                                                                      \
        _Pragma("unroll")                                                      \
        for (int i = 0; i < 2; ++i) {                                          \
            const int seg  = wid * 2 + i;                                      \
            const int rowB = seg * 16 + (lane >> 2);                           \
            const size_t go = (size_t)(n0 + rowB) * KPAD + kt_ * 32 + chB * 8; \
            gload16u(Bh + go, &ldsBh[PB][seg * 512 + lane * 8]);               \
            gload16u(Bl + go, &ldsBl[PB][seg * 512 + lane * 8]);               \
        }                                                                      \
    }

    STAGE(0, 0);
    __syncthreads();   // drains vmcnt(0): buf0 ready

    for (int kt = 0; kt < 32; ++kt) {
        const int cur = kt & 1;
        if (kt < 31) STAGE(kt + 1, cur ^ 1);   // issue next-tile loads (async)

        bf16x8_t ah[4], al[4], bh[4], bl[4];
#pragma unroll
        for (int f = 0; f < 4; ++f) {
            {   // A: fp32 read + in-register split
                const int row = wm + f * 16 + (lane & 15);
                const int c2  = (lane >> 4) * 2;
                const float4 p0 = *(const float4*)&ldsA[cur][row * 32 + ((c2)     ^ (row & 7)) * 4];
                const float4 p1 = *(const float4*)&ldsA[cur][row * 32 + ((c2 + 1) ^ (row & 7)) * 4];
                cvt8(p0, p1, ah[f], al[f]);
            }
            {   // B: pre-split bf16
                const int row = wn + f * 16 + (lane & 15);
                const int c   = (lane >> 4) ^ ((row >> 1) & 3);
                const int eo  = row * 32 + c * 8;
                bh[f] = *(const bf16x8_t*)&ldsBh[cur][eo];
                bl[f] = *(const bf16x8_t*)&ldsBl[cur][eo];
            }
        }
#pragma unroll
        for (int mf = 0; mf < 4; ++mf)
#pragma unroll
            for (int nf = 0; nf < 4; ++nf) {
                acc[mf][nf] = __builtin_amdgcn_mfma_f32_16x16x32_bf16(
                    ah[mf], bh[nf], acc[mf][nf], 0, 0, 0);
                acc[mf][nf] = __builtin_amdgcn_mfma_f32_16x16x32_bf16(
                    ah[mf], bl[nf], acc[mf][nf], 0, 0, 0);
                acc[mf][nf] = __builtin_amdgcn_mfma_f32_16x16x32_bf16(
                    al[mf], bh[nf], acc[mf][nf], 0, 0, 0);
            }
        __syncthreads();   // one barrier/K-step: drains next-buf loads too
    }
#undef STAGE

    // epilogue: C/D layout col=lane&15, row=(lane>>4)*4+q  [m89-verified]
#pragma unroll
    for (int nf = 0; nf < 4; ++nf) {
        const int gn = n0 + wn + nf * 16 + (lane & 15);
        const float bv = bias[gn];
#pragma unroll
        for (int mf = 0; mf < 4; ++mf) {
#pragma unroll
            for (int q = 0; q < 4; ++q) {
                const int gm = m0 + wm + mf * 16 + (lane >> 4) * 4 + q;
                C[(size_t)gm * G3 + gn] = acc[mf][nf][q] + bv;
            }
        }
    }
}

// ---------------------------------------------------------------------------
// W_hh [384][128] f32 -> Wt float4 layout [k4][g]
// ---------------------------------------------------------------------------
__global__ __launch_bounds__(256)
void transpose_whh(const float4* __restrict__ Whh4, float4* __restrict__ Wt4)
{
    const int idx = blockIdx.x * 256 + threadIdx.x;  // < 12288
    const int k4  = idx / G3;
    const int g   = idx - k4 * G3;
    Wt4[idx] = Whh4[g * 32 + k4];
}

// ---------------------------------------------------------------------------
// GRU scan + fused decoder (unchanged from r3, passed).
// ---------------------------------------------------------------------------
__global__ __launch_bounds__(768)
void gru_scan_dec(const float* __restrict__ xg,    // [MTOT][G3], m=b*SEQ+t
                  const float* __restrict__ h0,    // [BATCH][HID]
                  const float4* __restrict__ Wt,   // [32][384] float4
                  const float* __restrict__ b_hh,  // [G3]
                  const float* __restrict__ Wd,    // [4][2816]
                  const float* __restrict__ bd,    // [4]
                  float* __restrict__ out)         // [BATCH][4]
{
    __shared__ float hs[8][132];
    __shared__ float pp[8][2][G3];
    __shared__ float outsL[8][DECW];

    const int tid = threadIdx.x;
    const int b0  = blockIdx.x << 3;
    const int jh  = tid / G3;
    const int g   = tid - jh * G3;

    float4 w[16];
#pragma unroll
    for (int q = 0; q < 16; ++q) w[q] = Wt[(jh * 16 + q) * G3 + g];
    const float addb = jh ? b_hh[g] : 0.f;

    for (int idx = tid; idx < 1024; idx += 768)
        hs[idx >> 7][idx & 127] = h0[((size_t)(b0 + (idx >> 7)) << 7) + (idx & 127)];
    __syncthreads();

    const int r_0 = tid >> 7,         j_0 = tid & 127;
    const int r_1 = (tid + 768) >> 7, j_1 = tid & 127;
    const bool has1 = (tid < 256);

    for (int t = 0; t < SEQ; ++t) {
        const size_t base0 = ((size_t)(b0 + r_0) * SEQ + t) * G3;
        const float xr0 = xg[base0 + j_0];
        const float xz0 = xg[base0 + 128 + j_0];
        const float xn0 = xg[base0 + 256 + j_0];
        float xr1 = 0.f, xz1 = 0.f, xn1 = 0.f;
        if (has1) {
            const size_t base1 = ((size_t)(b0 + r_1) * SEQ + t) * G3;
            xr1 = xg[base1 + j_1];
            xz1 = xg[base1 + 128 + j_1];
            xn1 = xg[base1 + 256 + j_1];
        }

        float acc[8] = {0.f, 0.f, 0.f, 0.f, 0.f, 0.f, 0.f, 0.f};
#pragma unroll
        for (int q = 0; q < 16; ++q) {
            const float4 wq = w[q];
            const int ho = (jh * 16 + q) << 2;
#pragma unroll
            for (int r = 0; r < 8; ++r) {
                const float4 h4 = *(const float4*)&hs[r][ho];
                acc[r] = fmaf(h4.x, wq.x, fmaf(h4.y, wq.y,
                         fmaf(h4.z, wq.z, fmaf(h4.w, wq.w, acc[r]))));
            }
        }
#pragma unroll
        for (int r = 0; r < 8; ++r) pp[r][jh][g] = acc[r] + addb;
        __syncthreads();

        {
            const float hr = pp[r_0][0][j_0]       + pp[r_0][1][j_0];
            const float hz = pp[r_0][0][128 + j_0] + pp[r_0][1][128 + j_0];
            const float hn = pp[r_0][0][256 + j_0] + pp[r_0][1][256 + j_0];
            const float rr = 1.f / (1.f + __expf(-(xr0 + hr)));
            const float zz = 1.f / (1.f + __expf(-(xz0 + hz)));
            float vv = xn0 + rr * hn;
            vv = fminf(fmaxf(vv, -20.f), 20.f);
            const float e2 = __expf(2.f * vv);
            const float nn = (e2 - 1.f) / (e2 + 1.f);
            const float hp = hs[r_0][j_0];
            const float hnew = fmaf(zz, hp - nn, nn);
            hs[r_0][j_0] = hnew;
            outsL[r_0][(t << 7) + j_0] = hnew;
        }
        if (has1) {
            const float hr = pp[r_1][0][j_1]       + pp[r_1][1][j_1];
            const float hz = pp[r_1][0][128 + j_1] + pp[r_1][1][128 + j_1];
            const float hn = pp[r_1][0][256 + j_1] + pp[r_1][1][256 + j_1];
            const float rr = 1.f / (1.f + __expf(-(xr1 + hr)));
            const float zz = 1.f / (1.f + __expf(-(xz1 + hz)));
            float vv = xn1 + rr * hn;
            vv = fminf(fmaxf(vv, -20.f), 20.f);
            const float e2 = __expf(2.f * vv);
            const float nn = (e2 - 1.f) / (e2 + 1.f);
            const float hp = hs[r_1][j_1];
            const float hnew = fmaf(zz, hp - nn, nn);
            hs[r_1][j_1] = hnew;
            outsL[r_1][(t << 7) + j_1] = hnew;
        }
        __syncthreads();
    }

    const int wv = tid >> 6, lane = tid & 63;
    if (wv < 8) {
        float da[4] = {0.f, 0.f, 0.f, 0.f};
        for (int i = 0; i < 44; ++i) {
            const float v = outsL[wv][i * 64 + lane];
#pragma unroll
            for (int c = 0; c < 4; ++c)
                da[c] = fmaf(v, Wd[(size_t)c * DECW + i * 64 + lane], da[c]);
        }
#pragma unroll
        for (int c = 0; c < 4; ++c) {
            float v = da[c];
            for (int off = 32; off > 0; off >>= 1) v += __shfl_down(v, off, 64);
            if (lane == 0) out[(b0 + wv) * 4 + c] = v + bd[c];
        }
    }
}

// ---------------------------------------------------------------------------
extern "C" void kernel_launch(void* const* d_in, const int* in_sizes, int n_in,
                              void* d_out, int out_size, void* d_ws, size_t ws_size,
                              hipStream_t stream)
{
    const float* inputs = (const float*)d_in[0];   // [2048][22][1000]
    const float* h0     = (const float*)d_in[1];   // [1][2048][128]
    const float* W_ih   = (const float*)d_in[2];   // [384][1000]
    const float* W_hh   = (const float*)d_in[3];   // [384][128]
    const float* b_ih   = (const float*)d_in[4];   // [384]
    const float* b_hh   = (const float*)d_in[5];   // [384]
    const float* W_dec  = (const float*)d_in[6];   // [4][2816]
    const float* b_dec  = (const float*)d_in[7];   // [4]
    float* out = (float*)d_out;                    // [2048][4]

    char* ws = (char*)d_ws;
    const size_t szB = (size_t)G3 * KPAD * 2;                  // 786,432 B
    ushort* B_hi = (ushort*)ws;
    ushort* B_lo = (ushort*)(ws + szB);
    float4* Wt   = (float4*)(ws + 2 * szB);                    // 196,608 B
    float*  xgm  = (float*)(ws + 2 * szB + 196608);            // 69,206,016 B

    hipLaunchKernelGGL(split_rows, dim3(192), dim3(256), 0, stream,
                       W_ih, B_hi, B_lo, G3);
    hipLaunchKernelGGL(transpose_whh, dim3(48), dim3(256), 0, stream,
                       (const float4*)W_hh, Wt);
    hipLaunchKernelGGL(mfma_gemm, dim3(1056), dim3(256), 0, stream,
                       inputs, B_hi, B_lo, b_ih, xgm);
    hipLaunchKernelGGL(gru_scan_dec, dim3(BATCH / 8), dim3(768), 0, stream,
                       xgm, h0, (const float4*)Wt, b_hh, W_dec, b_dec, out);
}

// Round 5
// 478.656 us; speedup vs baseline: 1.8458x; 1.0635x over previous
//
#include <hip/hip_runtime.h>
#include <hip/hip_bf16.h>
#include <math.h>

#define BATCH 2048
#define SEQ   22
#define INSZ  1000
#define HID   128
#define G3    384            // 3*HID
#define MTOT  (BATCH*SEQ)    // 45056
#define KPAD  1024           // K padded (B only)
#define DECW  (SEQ*HID)      // 2816

typedef __attribute__((ext_vector_type(8))) short  bf16x8_t;
typedef __attribute__((ext_vector_type(4))) float  f32x4_t;
typedef __attribute__((ext_vector_type(8))) ushort us8_t;

typedef __attribute__((address_space(3))) ushort lds_us_t;
typedef __attribute__((address_space(1))) const ushort gbl_us_t;

__device__ inline void gload16u(const ushort* g, ushort* l) {
    __builtin_amdgcn_global_load_lds((gbl_us_t*)g, (lds_us_t*)l, 16, 0, 0);
}
__device__ inline void gload16f(const float* g, float* l) {
    __builtin_amdgcn_global_load_lds((gbl_us_t*)g, (lds_us_t*)l, 16, 0, 0);
}

__device__ inline ushort bf16_rn(float x) {
    uint u = __float_as_uint(x);
    uint r = u + 0x7FFFu + ((u >> 16) & 1u);
    return (ushort)(r >> 16);
}
__device__ inline void split1(float a, ushort& h, ushort& l) {
    h = bf16_rn(a);
    const float fh = __uint_as_float(((uint)h) << 16);
    l = bf16_rn(a - fh);
}

// 8 f32 (two float4, k-order) -> packed bf16 hi + lo fragments
__device__ inline void cvt8(const float4 p0, const float4 p1,
                            bf16x8_t& hi, bf16x8_t& lo)
{
    const float f[8] = {p0.x, p0.y, p0.z, p0.w, p1.x, p1.y, p1.z, p1.w};
    union { uint u[4]; bf16x8_t v; } H, L;
#pragma unroll
    for (int i = 0; i < 4; ++i) {
        const float2 v = make_float2(f[2 * i], f[2 * i + 1]);
        __hip_bfloat162 h2 = __float22bfloat162_rn(v);
        const uint w = *(const uint*)&h2;
        H.u[i] = w;
        const float fx = __uint_as_float(w << 16);
        const float fy = __uint_as_float(w & 0xFFFF0000u);
        const float2 r = make_float2(f[2 * i] - fx, f[2 * i + 1] - fy);
        __hip_bfloat162 l2 = __float22bfloat162_rn(r);
        L.u[i] = *(const uint*)&l2;
    }
    hi = H.v; lo = L.v;
}

// ---------------------------------------------------------------------------
// Split fp32 rows [nrows][INSZ] -> bf16 hi/lo [nrows][KPAD] (W_ih only).
// ---------------------------------------------------------------------------
__global__ __launch_bounds__(256)
void split_rows(const float* __restrict__ A, ushort* __restrict__ Hi,
                ushort* __restrict__ Lo, int nrows)
{
    const int nG = nrows * (KPAD / 8);
    for (int g = blockIdx.x * 256 + threadIdx.x; g < nG; g += gridDim.x * 256) {
        const int m = g >> 7;
        const int k = (g & 127) * 8;
        float4 v0 = make_float4(0.f, 0.f, 0.f, 0.f), v1 = v0;
        if (k < INSZ) {
            v0 = *(const float4*)&A[(size_t)m * INSZ + k];
            v1 = *(const float4*)&A[(size_t)m * INSZ + k + 4];
        }
        us8_t h, l;
        split1(v0.x, ((ushort*)&h)[0], ((ushort*)&l)[0]);
        split1(v0.y, ((ushort*)&h)[1], ((ushort*)&l)[1]);
        split1(v0.z, ((ushort*)&h)[2], ((ushort*)&l)[2]);
        split1(v0.w, ((ushort*)&h)[3], ((ushort*)&l)[3]);
        split1(v1.x, ((ushort*)&h)[4], ((ushort*)&l)[4]);
        split1(v1.y, ((ushort*)&h)[5], ((ushort*)&l)[5]);
        split1(v1.z, ((ushort*)&h)[6], ((ushort*)&l)[6]);
        split1(v1.w, ((ushort*)&h)[7], ((ushort*)&l)[7]);
        *(us8_t*)&Hi[(size_t)m * KPAD + k] = h;
        *(us8_t*)&Lo[(size_t)m * KPAD + k] = l;
    }
}

// ---------------------------------------------------------------------------
// MFMA GEMM, fused A-split, double-buffered with COUNTED vmcnt (T4):
// prefetch loads stay in flight across the barrier; never vmcnt(0) in the
// main loop. 128x128 tile, BK=32, 4 waves. 2 blocks/CU (64 KB LDS).
// ---------------------------------------------------------------------------
__global__ __launch_bounds__(256, 2)
void mfma_gemm(const float* __restrict__ A,      // [MTOT][1000] fp32
               const ushort* __restrict__ Bh,    // [G3][KPAD] bf16 hi
               const ushort* __restrict__ Bl,    // [G3][KPAD] bf16 lo
               const float* __restrict__ bias, float* __restrict__ C)
{
    __shared__ float  ldsA[2][4096];    // [buf][row*32 + slot4f32]  16 KB each
    __shared__ ushort ldsBh[2][4096];   // [buf][row*32 + c*8]        8 KB each
    __shared__ ushort ldsBl[2][4096];

    const int tid  = threadIdx.x;
    const int lane = tid & 63;
    const int wid  = tid >> 6;

    // XCD-bijective mapping: 1056 blocks = 8 XCD x 44 m-panels x 3 n
    const int d = blockIdx.x;
    const int xcd = d & 7, s = d >> 3;
    const int m0 = (xcd * 44 + s / 3) * 128;
    const int n0 = (s % 3) * 128;

    const int wm = (wid >> 1) * 64;
    const int wn = (wid & 1) * 64;

    const int gcA = (lane & 7) ^ (lane >> 3);            // A swizzled chunk
    const int chB = (lane & 3) ^ ((lane >> 3) & 3);      // B swizzled chunk

    f32x4_t acc[4][4];
#pragma unroll
    for (int i = 0; i < 4; ++i)
#pragma unroll
        for (int j = 0; j < 4; ++j) acc[i][j] = {0.f, 0.f, 0.f, 0.f};

    // 8 vmem ops per wave per STAGE (4 A + 4 B) -> vmcnt(8) = prev tile done
#define STAGE(KT, PB)                                                          \
    {                                                                          \
        const int kt_ = (KT);                                                  \
        _Pragma("unroll")                                                      \
        for (int u = 0; u < 4; ++u) {                                          \
            const int rowA = wid * 32 + u * 8 + (lane >> 3);                   \
            int gc = gcA;                                                      \
            if (kt_ == 31 && gc >= 2) gc = 0;  /* clamp: garbage*0, no OOB */  \
            gload16f(A + (size_t)(m0 + rowA) * INSZ + kt_ * 32 + gc * 4,       \
                     &ldsA[PB][(wid * 4 + u) * 256 + lane * 4]);               \
        }                                                                      \
        _Pragma("unroll")                                                      \
        for (int i = 0; i < 2; ++i) {                                          \
            const int seg  = wid * 2 + i;                                      \
            const int rowB = seg * 16 + (lane >> 2);                           \
            const size_t go = (size_t)(n0 + rowB) * KPAD + kt_ * 32 + chB * 8; \
            gload16u(Bh + go, &ldsBh[PB][seg * 512 + lane * 8]);               \
            gload16u(Bl + go, &ldsBl[PB][seg * 512 + lane * 8]);               \
        }                                                                      \
    }

    STAGE(0, 0);

    for (int kt = 0; kt < 32; ++kt) {
        const int cur = kt & 1;
        if (kt < 31) {
            STAGE(kt + 1, cur ^ 1);                       // stays in flight
            asm volatile("s_waitcnt vmcnt(8)" ::: "memory");  // cur's 8 done
        } else {
            asm volatile("s_waitcnt vmcnt(0)" ::: "memory");
        }
        __builtin_amdgcn_sched_barrier(0);
        __builtin_amdgcn_s_barrier();     // all waves: buf[cur] fully staged

        bf16x8_t ah[4], al[4], bh[4], bl[4];
#pragma unroll
        for (int f = 0; f < 4; ++f) {
            {   // A: fp32 read + in-register split
                const int row = wm + f * 16 + (lane & 15);
                const int c2  = (lane >> 4) * 2;
                const float4 p0 = *(const float4*)&ldsA[cur][row * 32 + ((c2)     ^ (row & 7)) * 4];
                const float4 p1 = *(const float4*)&ldsA[cur][row * 32 + ((c2 + 1) ^ (row & 7)) * 4];
                cvt8(p0, p1, ah[f], al[f]);
            }
            {   // B: pre-split bf16
                const int row = wn + f * 16 + (lane & 15);
                const int c   = (lane >> 4) ^ ((row >> 1) & 3);
                const int eo  = row * 32 + c * 8;
                bh[f] = *(const bf16x8_t*)&ldsBh[cur][eo];
                bl[f] = *(const bf16x8_t*)&ldsBl[cur][eo];
            }
        }
#pragma unroll
        for (int mf = 0; mf < 4; ++mf)
#pragma unroll
            for (int nf = 0; nf < 4; ++nf) {
                acc[mf][nf] = __builtin_amdgcn_mfma_f32_16x16x32_bf16(
                    ah[mf], bh[nf], acc[mf][nf], 0, 0, 0);
                acc[mf][nf] = __builtin_amdgcn_mfma_f32_16x16x32_bf16(
                    ah[mf], bl[nf], acc[mf][nf], 0, 0, 0);
                acc[mf][nf] = __builtin_amdgcn_mfma_f32_16x16x32_bf16(
                    al[mf], bh[nf], acc[mf][nf], 0, 0, 0);
            }
        // WAR: all waves must finish reading buf[cur] before next iteration's
        // DMA overwrites it. ds_reads are drained (MFMA deps); make explicit:
        asm volatile("s_waitcnt lgkmcnt(0)" ::: "memory");
        __builtin_amdgcn_sched_barrier(0);
        __builtin_amdgcn_s_barrier();
    }
#undef STAGE

    // epilogue: C/D layout col=lane&15, row=(lane>>4)*4+q  [m89-verified]
#pragma unroll
    for (int nf = 0; nf < 4; ++nf) {
        const int gn = n0 + wn + nf * 16 + (lane & 15);
        const float bv = bias[gn];
#pragma unroll
        for (int mf = 0; mf < 4; ++mf) {
#pragma unroll
            for (int q = 0; q < 4; ++q) {
                const int gm = m0 + wm + mf * 16 + (lane >> 4) * 4 + q;
                C[(size_t)gm * G3 + gn] = acc[mf][nf][q] + bv;
            }
        }
    }
}

// ---------------------------------------------------------------------------
// W_hh [384][128] f32 -> Wt float4 layout [k4][g]
// ---------------------------------------------------------------------------
__global__ __launch_bounds__(256)
void transpose_whh(const float4* __restrict__ Whh4, float4* __restrict__ Wt4)
{
    const int idx = blockIdx.x * 256 + threadIdx.x;  // < 12288
    const int k4  = idx / G3;
    const int g   = idx - k4 * G3;
    Wt4[idx] = Whh4[g * 32 + k4];
}

// ---------------------------------------------------------------------------
// GRU scan + fused decoder (unchanged from r4, passed).
// ---------------------------------------------------------------------------
__global__ __launch_bounds__(768)
void gru_scan_dec(const float* __restrict__ xg,    // [MTOT][G3], m=b*SEQ+t
                  const float* __restrict__ h0,    // [BATCH][HID]
                  const float4* __restrict__ Wt,   // [32][384] float4
                  const float* __restrict__ b_hh,  // [G3]
                  const float* __restrict__ Wd,    // [4][2816]
                  const float* __restrict__ bd,    // [4]
                  float* __restrict__ out)         // [BATCH][4]
{
    __shared__ float hs[8][132];
    __shared__ float pp[8][2][G3];
    __shared__ float outsL[8][DECW];

    const int tid = threadIdx.x;
    const int b0  = blockIdx.x << 3;
    const int jh  = tid / G3;
    const int g   = tid - jh * G3;

    float4 w[16];
#pragma unroll
    for (int q = 0; q < 16; ++q) w[q] = Wt[(jh * 16 + q) * G3 + g];
    const float addb = jh ? b_hh[g] : 0.f;

    for (int idx = tid; idx < 1024; idx += 768)
        hs[idx >> 7][idx & 127] = h0[((size_t)(b0 + (idx >> 7)) << 7) + (idx & 127)];
    __syncthreads();

    const int r_0 = tid >> 7,         j_0 = tid & 127;
    const int r_1 = (tid + 768) >> 7, j_1 = tid & 127;
    const bool has1 = (tid < 256);

    for (int t = 0; t < SEQ; ++t) {
        const size_t base0 = ((size_t)(b0 + r_0) * SEQ + t) * G3;
        const float xr0 = xg[base0 + j_0];
        const float xz0 = xg[base0 + 128 + j_0];
        const float xn0 = xg[base0 + 256 + j_0];
        float xr1 = 0.f, xz1 = 0.f, xn1 = 0.f;
        if (has1) {
            const size_t base1 = ((size_t)(b0 + r_1) * SEQ + t) * G3;
            xr1 = xg[base1 + j_1];
            xz1 = xg[base1 + 128 + j_1];
            xn1 = xg[base1 + 256 + j_1];
        }

        float acc[8] = {0.f, 0.f, 0.f, 0.f, 0.f, 0.f, 0.f, 0.f};
#pragma unroll
        for (int q = 0; q < 16; ++q) {
            const float4 wq = w[q];
            const int ho = (jh * 16 + q) << 2;
#pragma unroll
            for (int r = 0; r < 8; ++r) {
                const float4 h4 = *(const float4*)&hs[r][ho];
                acc[r] = fmaf(h4.x, wq.x, fmaf(h4.y, wq.y,
                         fmaf(h4.z, wq.z, fmaf(h4.w, wq.w, acc[r]))));
            }
        }
#pragma unroll
        for (int r = 0; r < 8; ++r) pp[r][jh][g] = acc[r] + addb;
        __syncthreads();

        {
            const float hr = pp[r_0][0][j_0]       + pp[r_0][1][j_0];
            const float hz = pp[r_0][0][128 + j_0] + pp[r_0][1][128 + j_0];
            const float hn = pp[r_0][0][256 + j_0] + pp[r_0][1][256 + j_0];
            const float rr = 1.f / (1.f + __expf(-(xr0 + hr)));
            const float zz = 1.f / (1.f + __expf(-(xz0 + hz)));
            float vv = xn0 + rr * hn;
            vv = fminf(fmaxf(vv, -20.f), 20.f);
            const float e2 = __expf(2.f * vv);
            const float nn = (e2 - 1.f) / (e2 + 1.f);
            const float hp = hs[r_0][j_0];
            const float hnew = fmaf(zz, hp - nn, nn);
            hs[r_0][j_0] = hnew;
            outsL[r_0][(t << 7) + j_0] = hnew;
        }
        if (has1) {
            const float hr = pp[r_1][0][j_1]       + pp[r_1][1][j_1];
            const float hz = pp[r_1][0][128 + j_1] + pp[r_1][1][128 + j_1];
            const float hn = pp[r_1][0][256 + j_1] + pp[r_1][1][256 + j_1];
            const float rr = 1.f / (1.f + __expf(-(xr1 + hr)));
            const float zz = 1.f / (1.f + __expf(-(xz1 + hz)));
            float vv = xn1 + rr * hn;
            vv = fminf(fmaxf(vv, -20.f), 20.f);
            const float e2 = __expf(2.f * vv);
            const float nn = (e2 - 1.f) / (e2 + 1.f);
            const float hp = hs[r_1][j_1];
            const float hnew = fmaf(zz, hp - nn, nn);
            hs[r_1][j_1] = hnew;
            outsL[r_1][(t << 7) + j_1] = hnew;
        }
        __syncthreads();
    }

    const int wv = tid >> 6, lane = tid & 63;
    if (wv < 8) {
        float da[4] = {0.f, 0.f, 0.f, 0.f};
        for (int i = 0; i < 44; ++i) {
            const float v = outsL[wv][i * 64 + lane];
#pragma unroll
            for (int c = 0; c < 4; ++c)
                da[c] = fmaf(v, Wd[(size_t)c * DECW + i * 64 + lane], da[c]);
        }
#pragma unroll
        for (int c = 0; c < 4; ++c) {
            float v = da[c];
            for (int off = 32; off > 0; off >>= 1) v += __shfl_down(v, off, 64);
            if (lane == 0) out[(b0 + wv) * 4 + c] = v + bd[c];
        }
    }
}

// ---------------------------------------------------------------------------
extern "C" void kernel_launch(void* const* d_in, const int* in_sizes, int n_in,
                              void* d_out, int out_size, void* d_ws, size_t ws_size,
                              hipStream_t stream)
{
    const float* inputs = (const float*)d_in[0];   // [2048][22][1000]
    const float* h0     = (const float*)d_in[1];   // [1][2048][128]
    const float* W_ih   = (const float*)d_in[2];   // [384][1000]
    const float* W_hh   = (const float*)d_in[3];   // [384][128]
    const float* b_ih   = (const float*)d_in[4];   // [384]
    const float* b_hh   = (const float*)d_in[5];   // [384]
    const float* W_dec  = (const float*)d_in[6];   // [4][2816]
    const float* b_dec  = (const float*)d_in[7];   // [4]
    float* out = (float*)d_out;                    // [2048][4]

    char* ws = (char*)d_ws;
    const size_t szB = (size_t)G3 * KPAD * 2;                  // 786,432 B
    ushort* B_hi = (ushort*)ws;
    ushort* B_lo = (ushort*)(ws + szB);
    float4* Wt   = (float4*)(ws + 2 * szB);                    // 196,608 B
    float*  xgm  = (float*)(ws + 2 * szB + 196608);            // 69,206,016 B

    hipLaunchKernelGGL(split_rows, dim3(192), dim3(256), 0, stream,
                       W_ih, B_hi, B_lo, G3);
    hipLaunchKernelGGL(transpose_whh, dim3(48), dim3(256), 0, stream,
                       (const float4*)W_hh, Wt);
    hipLaunchKernelGGL(mfma_gemm, dim3(1056), dim3(256), 0, stream,
                       inputs, B_hi, B_lo, b_ih, xgm);
    hipLaunchKernelGGL(gru_scan_dec, dim3(BATCH / 8), dim3(768), 0, stream,
                       xgm, h0, (const float4*)Wt, b_hh, W_dec, b_dec, out);
}